// Round 6
// baseline (91.463 us; speedup 1.0000x reference)
//
#include <hip/hip_runtime.h>
#include <hip/hip_fp16.h>

typedef _Float16 half8 __attribute__((ext_vector_type(8)));
typedef float f32x4 __attribute__((ext_vector_type(4)));

#define B_   8192
#define DIN  2048
#define C_   1000
#define CP   1024
#define NP2  512   // u,v interleaved rows

// ---- workspace layout (bytes) ---- (xh eliminated: gemm1 reads f32 x directly)
static const size_t OFF_WH  = 0;                                   // wh  [1024][2048] f16 (rows>=1000 zero)
static const size_t OFF_UVH = OFF_WH  + (size_t)CP * DIN * 2;      // uvh [512][1024]  f16
static const size_t OFF_PH  = OFF_UVH + (size_t)NP2 * CP * 2;      // predsh [8192][1024] f16
static const size_t OFF_SC  = OFF_PH  + (size_t)B_ * CP * 2;       // scores [8192] f32
static const size_t OFF_RS  = OFF_SC  + (size_t)B_ * 4;            // rowsum [8192] f32
static const size_t WS_NEED = OFF_RS  + (size_t)B_ * 4;

#define FENCE asm volatile("" ::: "memory")
#define BARRIER do { FENCE; __builtin_amdgcn_s_barrier(); FENCE; } while (0)
#define VMCNT(n) asm volatile("s_waitcnt vmcnt(" #n ")" ::: "memory")
#define LGKM0    asm volatile("s_waitcnt lgkmcnt(0)" ::: "memory")

__device__ __forceinline__ void gload16(const void* g, void* l) {
  __builtin_amdgcn_global_load_lds(
      (const __attribute__((address_space(1))) void*)g,
      (__attribute__((address_space(3))) void*)l, 16, 0, 0);
}

// ---------------- prep: f32 -> f16 (Wm, u/v) + zeroing (x no longer converted) ----------------
__global__ __launch_bounds__(256) void prep_kernel(
    const float* __restrict__ Wm,
    const float* __restrict__ u, const float* __restrict__ v,
    _Float16* __restrict__ wh, _Float16* __restrict__ uvh,
    float* __restrict__ scores, float* __restrict__ rowsum)
{
  const long NW  = (long)CP * DIN / 8;      //   262,144
  const long NUV = (long)NP2 * CP / 8;      //    65,536
  const long NZ  = 2 * (long)B_ / 8;        //     2,048
  const long T   = NW + NUV + NZ;
  for (long idx = (long)blockIdx.x * blockDim.x + threadIdx.x; idx < T;
       idx += (long)gridDim.x * blockDim.x) {
    if (idx < NW) {
      long e = idx * 8;
      int row = (int)(e >> 11);
      half8 h;
      if (row < C_) {
        float4 p0 = *(const float4*)(Wm + e);
        float4 p1 = *(const float4*)(Wm + e + 4);
        h[0] = (_Float16)p0.x; h[1] = (_Float16)p0.y; h[2] = (_Float16)p0.z; h[3] = (_Float16)p0.w;
        h[4] = (_Float16)p1.x; h[5] = (_Float16)p1.y; h[6] = (_Float16)p1.z; h[7] = (_Float16)p1.w;
      } else {
        h = (half8)(_Float16)0.f;
      }
      *(half8*)(wh + e) = h;
    } else if (idx < NW + NUV) {
      long e = (idx - NW) * 8;
      int j = (int)(e >> 10);
      int k = (int)(e & 1023);
      const float* src = (j & 1) ? v : u;
      int p = j >> 1;
      half8 h;
      #pragma unroll
      for (int t = 0; t < 8; ++t) {
        int kk = k + t;
        h[t] = (kk < C_) ? (_Float16)src[(size_t)p * C_ + kk] : (_Float16)0.f;
      }
      *(half8*)(uvh + e) = h;
    } else {
      long e = (idx - NW - NUV) * 8;
      float4 z = {0.f, 0.f, 0.f, 0.f};
      if (e < B_) {
        *(float4*)(scores + e) = z; *(float4*)(scores + e + 4) = z;
      } else {
        long r = e - B_;
        *(float4*)(rowsum + r) = z; *(float4*)(rowsum + r + 4) = z;
      }
    }
  }
}

// ---------------- main GEMM: preds = x @ wh^T + bm (A converted in-kernel) ----------------
// 256x128 tile, BK=64, 512 threads = 8 waves (4M x 2N), wave tile 64x64.
// LDS: 3 A-buffers (32KB) + 3 B-buffers (16KB) = 144KB.
// A path: 8x global_load_dwordx4 (f32, issued tile t for t+2, ~4 phases of
// slack >> 900cyc HBM) -> RTN cvt -> swizzled ds_write_b128 at t+1's P0,
// published via lgkmcnt(0)+barrier, read at t+1 P2 / t+2 P0.
// B path: global_load_lds, issued at P2 for t+2, waited via counted vmcnt(10)
// at P3 (FIFO: [B2(t+1), A8(t+2), B2(t+2)] = 12 outstanding -> drain 2 oldest).
// 4 phases/tile, each {ds_reads + issue || barrier || setprio 8 MFMA}.
__global__ __launch_bounds__(512) void gemm1_kernel(
    const float* __restrict__ x, const _Float16* __restrict__ wh,
    const float* __restrict__ bmv, float* __restrict__ preds,
    _Float16* __restrict__ predsh, float* __restrict__ rowsum)
{
  __shared__ _Float16 lds[3 * 16384 + 3 * 8192];   // A bufs @ i*32768B, B bufs @ 98304 + i*16384B
  char* const LB = (char*)lds;
  const int tid  = threadIdx.x;
  const int lane = tid & 63;
  const int w    = tid >> 6;       // 0..7
  const int wm   = w >> 1;         // 0..3 (M quarter, 64 rows)
  const int wn   = w & 1;          // 0..1 (N half, 64 cols)
  const int bm0  = blockIdx.x * 256;
  const int bn0  = blockIdx.y * 128;

  f32x4 acc[4][4] = {};

  // A f32 sources: slot = j*512+tid -> row = slot>>3 (0..255), col8 = slot&7.
  // Thread loads 8 consecutive f32 of one row (2x dwordx4), cvt -> one
  // ds_write_b128 at swizzled dest (identical LDS image to the old
  // pre-swizzled-source path; read offsets unchanged).
  const float* srcAx[4];
  int dstAoff[4];
  #pragma unroll
  for (int j = 0; j < 4; ++j) {
    int slot = j * 512 + tid;
    int row  = slot >> 3;
    int col8 = slot & 7;
    srcAx[j]   = x + (size_t)(bm0 + row) * DIN + col8 * 8;
    dstAoff[j] = row * 128 + ((col8 << 4) ^ ((row & 7) << 4));
  }
  // B sources: pre-swizzled global addr, linear gload_lds dest
  const _Float16* srcB[2];
  #pragma unroll
  for (int k = 0; k < 2; ++k) {
    int slot = k * 512 + tid;
    int row  = slot >> 3;              // 0..127
    int cb   = (slot & 7) << 4;
    int scb  = cb ^ ((row & 7) << 4);
    srcB[k] = wh + (size_t)(bn0 + row) * DIN + (scb >> 1);
  }

  // ds_read fragment byte offsets (A within 32KB buf, B within 16KB buf)
  int aoff[4][2], boff[4][2];
  #pragma unroll
  for (int m = 0; m < 4; ++m) {
    #pragma unroll
    for (int ks = 0; ks < 2; ++ks) {
      int ra = wm * 64 + m * 16 + (lane & 15);
      int kb = ks * 64 + (lane >> 4) * 16;
      aoff[m][ks] = ra * 128 + (kb ^ ((ra & 7) << 4));
    }
  }
  #pragma unroll
  for (int n = 0; n < 4; ++n) {
    #pragma unroll
    for (int ks = 0; ks < 2; ++ks) {
      int rb = wn * 64 + n * 16 + (lane & 15);
      int kb = ks * 64 + (lane >> 4) * 16;
      boff[n][ks] = rb * 128 + (kb ^ ((rb & 7) << 4));
    }
  }

  half8 aLa[2][2], aLb[2][2], aHf[2][2], bLf[2][2], bHf[2][2];
  float4 af[4][2];   // in-flight f32 A tile (32 VGPR)

  auto issueA01 = [&]() {
    af[0][0] = *(const float4*)srcAx[0]; af[0][1] = *(const float4*)(srcAx[0] + 4);
    af[1][0] = *(const float4*)srcAx[1]; af[1][1] = *(const float4*)(srcAx[1] + 4);
  };
  auto issueA23 = [&]() {
    af[2][0] = *(const float4*)srcAx[2]; af[2][1] = *(const float4*)(srcAx[2] + 4);
    af[3][0] = *(const float4*)srcAx[3]; af[3][1] = *(const float4*)(srcAx[3] + 4);
    #pragma unroll
    for (int j = 0; j < 4; ++j) srcAx[j] += 64;
  };
  auto cvtWriteA = [&](int cbuf) {
    char* base = LB + cbuf * 32768;
    #pragma unroll
    for (int j = 0; j < 4; ++j) {
      half8 h;
      h[0] = (_Float16)af[j][0].x; h[1] = (_Float16)af[j][0].y;
      h[2] = (_Float16)af[j][0].z; h[3] = (_Float16)af[j][0].w;
      h[4] = (_Float16)af[j][1].x; h[5] = (_Float16)af[j][1].y;
      h[6] = (_Float16)af[j][1].z; h[7] = (_Float16)af[j][1].w;
      *(half8*)(base + dstAoff[j]) = h;
    }
  };
  auto stB = [&](int cbuf) {
    gload16(srcB[0], LB + 98304 + cbuf * 16384 + w * 1024);
    gload16(srcB[1], LB + 98304 + cbuf * 16384 + 8192 + w * 1024);
    srcB[0] += 64; srcB[1] += 64;
  };
  auto rdAH = [&](const char* b) {
    #pragma unroll
    for (int m = 0; m < 2; ++m)
      #pragma unroll
      for (int ks = 0; ks < 2; ++ks)
        aHf[m][ks] = *(const half8*)(b + aoff[m + 2][ks]);
  };
  auto rdBH = [&](const char* b) {
    #pragma unroll
    for (int n = 0; n < 2; ++n)
      #pragma unroll
      for (int ks = 0; ks < 2; ++ks)
        bHf[n][ks] = *(const half8*)(b + boff[n + 2][ks]);
  };
  auto rdAL = [&](const char* b, half8 (&d)[2][2]) {
    #pragma unroll
    for (int m = 0; m < 2; ++m)
      #pragma unroll
      for (int ks = 0; ks < 2; ++ks)
        d[m][ks] = *(const half8*)(b + aoff[m][ks]);
  };
  auto rdBL = [&](const char* b) {
    #pragma unroll
    for (int n = 0; n < 2; ++n)
      #pragma unroll
      for (int ks = 0; ks < 2; ++ks)
        bLf[n][ks] = *(const half8*)(b + boff[n][ks]);
  };
  auto mfLL = [&](half8 (&aL)[2][2]) {
    #pragma unroll
    for (int m = 0; m < 2; ++m)
      #pragma unroll
      for (int n = 0; n < 2; ++n)
        #pragma unroll
        for (int ks = 0; ks < 2; ++ks)
          acc[m][n] = __builtin_amdgcn_mfma_f32_16x16x32_f16(aL[m][ks], bLf[n][ks], acc[m][n], 0, 0, 0);
  };
  auto mfHL = [&]() {
    #pragma unroll
    for (int m = 0; m < 2; ++m)
      #pragma unroll
      for (int n = 0; n < 2; ++n)
        #pragma unroll
        for (int ks = 0; ks < 2; ++ks)
          acc[m + 2][n] = __builtin_amdgcn_mfma_f32_16x16x32_f16(aHf[m][ks], bLf[n][ks], acc[m + 2][n], 0, 0, 0);
  };
  auto mfLH = [&](half8 (&aL)[2][2]) {
    #pragma unroll
    for (int m = 0; m < 2; ++m)
      #pragma unroll
      for (int n = 0; n < 2; ++n)
        #pragma unroll
        for (int ks = 0; ks < 2; ++ks)
          acc[m][n + 2] = __builtin_amdgcn_mfma_f32_16x16x32_f16(aL[m][ks], bHf[n][ks], acc[m][n + 2], 0, 0, 0);
  };
  auto mfHH = [&]() {
    #pragma unroll
    for (int m = 0; m < 2; ++m)
      #pragma unroll
      for (int n = 0; n < 2; ++n)
        #pragma unroll
        for (int ks = 0; ks < 2; ++ks)
          acc[m + 2][n + 2] = __builtin_amdgcn_mfma_f32_16x16x32_f16(aHf[m][ks], bHf[n][ks], acc[m + 2][n + 2], 0, 0, 0);
  };

  #define PRIO1 __builtin_amdgcn_s_setprio(1)
  #define PRIO0 __builtin_amdgcn_s_setprio(0)

  // ---- prologue: A(0)->bufA0 via regs, B(0)->bufB0; A(1) in regs, B(1) flying ----
  issueA01(); issueA23();      // A(0): 8 loads
  stB(0);                      // B(0): 2 gloads
  VMCNT(2);                    // A(0) regs ready (B(0) outstanding)
  cvtWriteA(0);
  issueA01(); issueA23();      // A(1): 8 loads
  stB(1);                      // B(1): 2 gloads
  VMCNT(10);                   // B(0) in LDS (outstanding: A8(1)+B2(1)=10)
  LGKM0;                       // A(0) ds_writes complete
  BARRIER;
  rdAL(LB, aLa);
  rdBL(LB + 98304);

  // ---- main loop: tiles 0..29, two per iteration ----
  int c0 = 0;
  #pragma unroll 1
  for (int t = 0; t < 30; t += 2) {
    const int c1 = (c0 == 2) ? 0 : c0 + 1;
    const int c2 = (c1 == 2) ? 0 : c1 + 1;
    const char* pA0 = LB + c0 * 32768;
    const char* pA1 = LB + c1 * 32768;
    const char* pA2 = LB + c2 * 32768;
    const char* pB0 = LB + 98304 + c0 * 16384;
    const char* pB1 = LB + 98304 + c1 * 16384;
    const char* pB2 = LB + 98304 + c2 * 16384;

    // ===== even tile t (cur = c0, aLa) =====
    VMCNT(2);                          // A f32(t+1) ready
    cvtWriteA(c1);
    rdAH(pA0);
    issueA01();                        // A(t+2) first half
    LGKM0; BARRIER;
    PRIO1; mfLL(aLa); PRIO0;

    rdBH(pB0);
    issueA23();                        // A(t+2) second half
    BARRIER;
    PRIO1; mfHL(); PRIO0;

    rdAL(pA1, aLb);
    stB(c2);                           // B(t+2)
    BARRIER;
    PRIO1; mfLH(aLa); PRIO0;

    VMCNT(10);                         // B(t+1) in LDS
    BARRIER;
    rdBL(pB1);
    PRIO1; mfHH(); PRIO0;

    // ===== odd tile t+1 (cur = c1, aLb) =====
    VMCNT(2);                          // A f32(t+2) ready
    cvtWriteA(c2);
    rdAH(pA1);
    issueA01();                        // A(t+3) first half
    LGKM0; BARRIER;
    PRIO1; mfLL(aLb); PRIO0;

    rdBH(pB1);
    issueA23();                        // A(t+3) second half
    BARRIER;
    PRIO1; mfHL(); PRIO0;

    rdAL(pA2, aLa);
    stB(c0);                           // B(t+3) -> bufB[(t+3)%3] = c0
    BARRIER;
    PRIO1; mfLH(aLb); PRIO0;

    VMCNT(10);                         // B(t+2) in LDS
    BARRIER;
    rdBL(pB2);
    PRIO1; mfHH(); PRIO0;

    c0 = c2;
  }

  // ---- tail: tiles 30 (buf0) and 31 (buf1) ----
  {
    const char* pA0 = LB;
    const char* pA1 = LB + 32768;
    const char* pB0 = LB + 98304;
    const char* pB1 = LB + 98304 + 16384;
    // tile 30
    VMCNT(2);                          // A f32(31) ready (B(31) outstanding)
    cvtWriteA(1);
    rdAH(pA0);
    LGKM0; BARRIER;
    PRIO1; mfLL(aLa); PRIO0;
    rdBH(pB0);
    BARRIER;
    PRIO1; mfHL(); PRIO0;
    rdAL(pA1, aLb);
    BARRIER;
    PRIO1; mfLH(aLa); PRIO0;
    VMCNT(0);                          // B(31) in LDS
    BARRIER;
    rdBL(pB1);
    PRIO1; mfHH(); PRIO0;
    // tile 31 (no staging, no barriers needed)
    rdAH(pA1); rdBH(pB1);
    mfLL(aLb); mfHL(); mfLH(aLb); mfHH();
  }

  // ---- epilogue: bias add, f32 preds, f16 predsh, rowsum partials ----
  float rp[4][4] = {};
  #pragma unroll
  for (int m = 0; m < 4; ++m) {
    #pragma unroll
    for (int n = 0; n < 4; ++n) {
      f32x4 d = acc[m][n];
      int gc = bn0 + wn * 64 + n * 16 + (lane & 15);
      float bias = (gc < C_) ? bmv[gc] : 0.f;
      #pragma unroll
      for (int j = 0; j < 4; ++j) {
        int gr = bm0 + wm * 64 + m * 16 + (lane >> 4) * 4 + j;
        float val = d[j] + bias;
        predsh[(size_t)gr * CP + gc] = (_Float16)val;
        if (gc < C_) preds[(size_t)gr * C_ + gc] = val;
        rp[m][j] += val;
      }
    }
  }
  #pragma unroll
  for (int m = 0; m < 4; ++m) {
    #pragma unroll
    for (int j = 0; j < 4; ++j) {
      float s = rp[m][j];
      s += __shfl_xor(s, 1); s += __shfl_xor(s, 2);
      s += __shfl_xor(s, 4); s += __shfl_xor(s, 8);
      if ((lane & 15) == 0) {
        int gr = bm0 + wm * 64 + m * 16 + (lane >> 4) * 4 + j;
        atomicAdd(&rowsum[gr], s);
      }
    }
  }
  #undef PRIO1
  #undef PRIO0
}

// ---------------- gating GEMM: scores partials (r2-validated) ----------------
__global__ __launch_bounds__(256) void gemm2_kernel(
    const _Float16* __restrict__ predsh, const _Float16* __restrict__ uvh,
    const float* __restrict__ wv, float* __restrict__ scores)
{
  __shared__ _Float16 sA[2][64 * 64];
  __shared__ _Float16 sB[2][128 * 64];
  const int tid  = threadIdx.x;
  const int lane = tid & 63;
  const int w    = tid >> 6;
  const int wm   = w >> 1, wn = w & 1;   // wave owns 32x64
  const int bm0  = blockIdx.x * 64;
  const int bn0  = blockIdx.y * 128;

  f32x4 acc[2][4] = {};

  const _Float16* srcA[2]; const _Float16* srcB[4];
  #pragma unroll
  for (int i = 0; i < 2; ++i) {
    int slot = i * 256 + tid;
    int row  = slot >> 3;
    int cb   = (slot & 7) << 4;
    int scb  = cb ^ ((row & 7) << 4);
    srcA[i] = predsh + (size_t)(bm0 + row) * CP + (scb >> 1);
  }
  #pragma unroll
  for (int i = 0; i < 4; ++i) {
    int slot = i * 256 + tid;
    int row  = slot >> 3;
    int cb   = (slot & 7) << 4;
    int scb  = cb ^ ((row & 7) << 4);
    srcB[i] = uvh + (size_t)(bn0 + row) * CP + (scb >> 1);
  }
  int aoff[2][2], boff[4][2];
  #pragma unroll
  for (int ks = 0; ks < 2; ++ks) {
    int kb = ks * 64 + (lane >> 4) * 16;
    #pragma unroll
    for (int mi = 0; mi < 2; ++mi) {
      int ra = wm * 32 + mi * 16 + (lane & 15);
      aoff[mi][ks] = ra * 128 + (kb ^ ((ra & 7) << 4));
    }
    #pragma unroll
    for (int ni = 0; ni < 4; ++ni) {
      int rb = wn * 64 + ni * 16 + (lane & 15);
      boff[ni][ks] = rb * 128 + (kb ^ ((rb & 7) << 4));
    }
  }

  auto stage = [&](int c) {
    #pragma unroll
    for (int i = 0; i < 2; ++i) {
      gload16(srcA[i], &sA[c][(i * 4 + w) * 512]);
      srcA[i] += 64;
    }
    #pragma unroll
    for (int i = 0; i < 4; ++i) {
      gload16(srcB[i], &sB[c][(i * 4 + w) * 512]);
      srcB[i] += 64;
    }
  };

  auto compute = [&](int c) {
    const char* bA = (const char*)&sA[c][0];
    const char* bB = (const char*)&sB[c][0];
    #pragma unroll
    for (int ks = 0; ks < 2; ++ks) {
      half8 a[2], b[4];
      #pragma unroll
      for (int mi = 0; mi < 2; ++mi) a[mi] = *(const half8*)(bA + aoff[mi][ks]);
      #pragma unroll
      for (int ni = 0; ni < 4; ++ni) b[ni] = *(const half8*)(bB + boff[ni][ks]);
      #pragma unroll
      for (int mi = 0; mi < 2; ++mi)
        #pragma unroll
        for (int ni = 0; ni < 4; ++ni)
          acc[mi][ni] = __builtin_amdgcn_mfma_f32_16x16x32_f16(a[mi], b[ni], acc[mi][ni], 0, 0, 0);
    }
  };

  const int NT = CP / 64;   // 16
  stage(0);
  #pragma unroll 1
  for (int kt = 0; kt < NT; kt += 2) {
    stage(1);
    asm volatile("s_waitcnt vmcnt(6)" ::: "memory");
    BARRIER;
    compute(0);
    BARRIER;
    if (kt + 2 < NT) {
      stage(0);
      asm volatile("s_waitcnt vmcnt(6)" ::: "memory");
    } else {
      asm volatile("s_waitcnt vmcnt(0)" ::: "memory");
    }
    BARRIER;
    compute(1);
    BARRIER;
  }

  float sp[2][4] = {};
  #pragma unroll
  for (int mi = 0; mi < 2; ++mi) {
    #pragma unroll
    for (int ni = 0; ni < 4; ++ni) {
      f32x4 d = acc[mi][ni];
      int gc = bn0 + wn * 64 + ni * 16 + (lane & 15);   // even=u col, odd=v col
      float wq = wv[gc >> 1];
      bool even = ((gc & 1) == 0);
      #pragma unroll
      for (int j = 0; j < 4; ++j) {
        float t  = d[j];
        float pr = __shfl_xor(t, 1);
        float th = 2.f / (1.f + __expf(-2.f * t)) - 1.f;
        float sg = 1.f / (1.f + __expf(-pr));
        sp[mi][j] += even ? (th * sg * wq) : 0.f;
      }
    }
  }
  #pragma unroll
  for (int mi = 0; mi < 2; ++mi) {
    #pragma unroll
    for (int j = 0; j < 4; ++j) {
      float s = sp[mi][j];
      s += __shfl_xor(s, 1); s += __shfl_xor(s, 2);
      s += __shfl_xor(s, 4); s += __shfl_xor(s, 8);
      if ((lane & 15) == 0) {
        int gr = bm0 + wm * 32 + mi * 16 + (lane >> 4) * 4 + j;
        atomicAdd(&scores[gr], s);
      }
    }
  }
}

// ---------------- final: softmax over scores, weighted rowsum ----------------
__global__ __launch_bounds__(1024) void final_kernel(
    const float* __restrict__ scores, const float* __restrict__ rowsum,
    float* __restrict__ out)
{
  __shared__ float red[16], red2[16];
  const int t = threadIdx.x;
  const int lane = t & 63, wid = t >> 6;
  float s[8];
  float m = -3.4e38f;
  #pragma unroll
  for (int i = 0; i < 8; ++i) { s[i] = scores[t + i * 1024]; m = fmaxf(m, s[i]); }
  #pragma unroll
  for (int off = 1; off < 64; off <<= 1) m = fmaxf(m, __shfl_xor(m, off));
  if (lane == 0) red[wid] = m;
  __syncthreads();
  #pragma unroll
  for (int i = 0; i < 16; ++i) m = fmaxf(m, red[i]);
  __syncthreads();

  float se = 0.f, sr = 0.f;
  #pragma unroll
  for (int i = 0; i < 8; ++i) {
    float e = __expf(s[i] - m);
    se += e;
    sr += e * rowsum[t + i * 1024];
  }
  #pragma unroll
  for (int off = 1; off < 64; off <<= 1) { se += __shfl_xor(se, off); sr += __shfl_xor(sr, off); }
  if (lane == 0) { red[wid] = se; red2[wid] = sr; }
  __syncthreads();
  if (t == 0) {
    float tse = 0.f, tsr = 0.f;
    for (int i = 0; i < 16; ++i) { tse += red[i]; tsr += red2[i]; }
    out[0] = tsr / tse;
  }
}

extern "C" void kernel_launch(void* const* d_in, const int* in_sizes, int n_in,
                              void* d_out, int out_size, void* d_ws, size_t ws_size,
                              hipStream_t stream)
{
  const float* x   = (const float*)d_in[0];
  const float* Wm  = (const float*)d_in[1];
  const float* bmv = (const float*)d_in[2];
  const float* u   = (const float*)d_in[3];
  const float* v   = (const float*)d_in[4];
  const float* wv  = (const float*)d_in[5];
  float* out = (float*)d_out;

  if (ws_size < WS_NEED) return;

  char* ws = (char*)d_ws;
  _Float16* wh     = (_Float16*)(ws + OFF_WH);
  _Float16* uvh    = (_Float16*)(ws + OFF_UVH);
  _Float16* predsh = (_Float16*)(ws + OFF_PH);
  float*    scores = (float*)(ws + OFF_SC);
  float*    rowsum = (float*)(ws + OFF_RS);

  prep_kernel<<<1288, 256, 0, stream>>>(Wm, u, v, wh, uvh, scores, rowsum);
  gemm1_kernel<<<dim3(32, 8), 512, 0, stream>>>(x, wh, bmv, out, predsh, rowsum);
  gemm2_kernel<<<dim3(128, 4), 256, 0, stream>>>(predsh, uvh, wv, scores);
  final_kernel<<<1, 1024, 0, stream>>>(scores, rowsum, out + (size_t)B_ * C_);
}